// Round 10
// baseline (1499.241 us; speedup 1.0000x reference)
//
#include <hip/hip_runtime.h>
#include <hip/hip_bf16.h>
#include <math.h>

typedef unsigned short u16;
typedef __attribute__((ext_vector_type(8))) short bfrag;     // 8 bf16 (4 VGPR)
typedef __attribute__((ext_vector_type(16))) float facc16;   // 16 fp32 acc
typedef const __attribute__((address_space(1))) void* gaddr_t;
typedef __attribute__((address_space(3))) void* laddr_t;

#define F_RELU   1
#define F_ROWSC  4   // *= rsc[m]
#define F_SIMSC  8   // *= rsc[m]*csc[n]
#define F_RESID2 32  // += bf16 residH + residL
#define F_BIASM  64  // bias indexed by gm (row) instead of gn

__device__ __forceinline__ u16 f2bf(float f) {
  __hip_bfloat16 h = __float2bfloat16(f);
  return *reinterpret_cast<u16*>(&h);
}
__device__ __forceinline__ float bf2f(u16 u) {
  __hip_bfloat16 h = *reinterpret_cast<__hip_bfloat16*>(&u);
  return __bfloat162float(h);
}
__device__ __forceinline__ float wsum(float v) {
#pragma unroll
  for (int o = 32; o; o >>= 1) v += __shfl_xor(v, o);
  return v;
}
__device__ __forceinline__ float wmaxf(float v) {
#pragma unroll
  for (int o = 32; o; o >>= 1) v = fmaxf(v, __shfl_xor(v, o));
  return v;
}

struct GSeg {
  const u16* A; const u16* B;
  long sA, sB;          // per-z strides
  int lda, ldb, K;      // K % 64 == 0
  int hA, hB;           // per-head offsets (headBits mode)
};

// ---------------------------------------------------------------------------
// bf16 MFMA GEMM, up to 3 K-segments: C = epi(alpha * sum_s A_s @ B_s^T)
// 256 thr = 4 waves; tile 128x128; BK=64; dbuf LDS 2x32KB; 32x32x16 MFMA.
// R10: XCD-aware block swizzle (z==1 grids): consecutive ids round-robin
// over 8 XCDs; remap so the gy column-blocks sharing one A row-strip occupy
// CONSECUTIVE slots on ONE XCD -> strip stays in that XCD's 4MB L2, glds
// hits L2 (~200cyc) instead of HBM (~900cyc), shrinking the dbuf barrier
// drain. [R9 PMC: FFN1 FETCH=103MB vs 35MB ideal = 3x A over-fetch.]
// ---------------------------------------------------------------------------
__global__ __launch_bounds__(256)
void bgemm_k(GSeg s0, GSeg s1, GSeg s2,
             const float* __restrict__ bias,
             const u16* __restrict__ residH, const u16* __restrict__ residL,
             const float* __restrict__ rsc, const float* __restrict__ csc,
             float* __restrict__ Cf, u16* __restrict__ Cb, u16* __restrict__ Cb2,
             int ldc, long sC, int hC, int headBits, int sS,
             float alpha, int flags, int Mstore)
{
  const int zAll = blockIdx.z;
  const int hIdx = headBits ? (zAll & 1) : 0;
  const int z    = headBits ? (zAll >> 1) : zAll;
  const long cofs = (long)z * sC + (long)hIdx * hC;
  const float* rs = rsc ? rsc + (long)z * sS : nullptr;
  const float* cs = csc ? csc + (long)z * sS : nullptr;

  // --- XCD-aware swizzle (identity for z>1 grids) ---
  int bx = blockIdx.x, by = blockIdx.y;
  if (gridDim.z == 1) {
    int id = bx + gridDim.x * by;
    int g = id & 7, s = id >> 3;
    if ((gridDim.x & 7) == 0) {            // group column-blocks per A-strip
      int t = gridDim.y;
      bx = g + 8 * (s / t);
      by = s % t;
    } else if ((gridDim.y & 7) == 0) {     // group row-blocks per B-strip
      int t = gridDim.x;
      by = g + 8 * (s / t);
      bx = s % t;
    }
  }
  const int m0 = bx * 128, n0 = by * 128;

  __shared__ u16 As[2][128 * 64];
  __shared__ u16 Bs[2][128 * 64];

  const int tid  = threadIdx.x;
  const int wave = tid >> 6, lane = tid & 63;
  const int wrow = (wave >> 1) * 64, wcol = (wave & 1) * 64;

  const u16* ApS[3]; const u16* BpS[3]; int ldaS[3], ldbS[3];
  ApS[0] = s0.A + (long)z * s0.sA + (long)hIdx * s0.hA;
  BpS[0] = s0.B + (long)z * s0.sB + (long)hIdx * s0.hB;
  ldaS[0] = s0.lda; ldbS[0] = s0.ldb;
  ApS[1] = s1.A ? s1.A + (long)z * s1.sA + (long)hIdx * s1.hA : nullptr;
  BpS[1] = s1.B ? s1.B + (long)z * s1.sB + (long)hIdx * s1.hB : nullptr;
  ldaS[1] = s1.lda; ldbS[1] = s1.ldb;
  ApS[2] = s2.A ? s2.A + (long)z * s2.sA + (long)hIdx * s2.hA : nullptr;
  BpS[2] = s2.B ? s2.B + (long)z * s2.sB + (long)hIdx * s2.hB : nullptr;
  ldaS[2] = s2.lda; ldbS[2] = s2.ldb;
  const int n0i = s0.K >> 6, n1i = n0i + (s1.K >> 6);
  const int nIt = n1i + (s2.K >> 6);

  const int lrow = lane >> 3;          // 0..7
  const int lgrp = lane & 7;           // 0..7

  facc16 acc[2][2];
#pragma unroll
  for (int i = 0; i < 2; ++i)
#pragma unroll
    for (int j = 0; j < 2; ++j) acc[i][j] = (facc16)(0.f);

  const int l31 = lane & 31, l5 = lane >> 5;

  auto stage = [&](int buf, int it) {
    int sidx, base;
    if (it < n0i)      { sidx = 0; base = 0; }
    else if (it < n1i) { sidx = 1; base = n0i; }
    else               { sidx = 2; base = n1i; }
    const int k0 = (it - base) << 6;
    const u16* Ab = ApS[sidx];
    const u16* Bb = BpS[sidx];
    const int la = ldaS[sidx], lb = ldbS[sidx];
#pragma unroll
    for (int ss = 0; ss < 4; ++ss) {
      int rloc = wave * 32 + ss * 8;
      int row  = rloc + lrow;
      int g    = lgrp ^ ((row >> 1) & 7);
      __builtin_amdgcn_global_load_lds(
          (gaddr_t)(const void*)(Ab + (long)(m0 + row) * la + k0 + g * 8),
          (laddr_t)(As[buf] + rloc * 64), 16, 0, 0);
      __builtin_amdgcn_global_load_lds(
          (gaddr_t)(const void*)(Bb + (long)(n0 + row) * lb + k0 + g * 8),
          (laddr_t)(Bs[buf] + rloc * 64), 16, 0, 0);
    }
  };

  stage(0, 0);
  for (int it = 0; it < nIt; ++it) {
    const int buf = it & 1;
    __syncthreads();                      // drains glds; buf ready
    if (it + 1 < nIt) stage(buf ^ 1, it + 1);

#pragma unroll
    for (int ks = 0; ks < 4; ++ks) {      // K=16 per MFMA step
      const int gg = ks * 2 + l5;
      bfrag af[2], bb[2];
#pragma unroll
      for (int mt = 0; mt < 2; ++mt) {
        int r = wrow + mt * 32 + l31;
        int slot = gg ^ ((r >> 1) & 7);
        af[mt] = *(const bfrag*)&As[buf][r * 64 + slot * 8];
      }
#pragma unroll
      for (int nt = 0; nt < 2; ++nt) {
        int r = wcol + nt * 32 + l31;
        int slot = gg ^ ((r >> 1) & 7);
        bb[nt] = *(const bfrag*)&Bs[buf][r * 64 + slot * 8];
      }
#pragma unroll
      for (int mt = 0; mt < 2; ++mt)
#pragma unroll
        for (int nt = 0; nt < 2; ++nt)
          acc[mt][nt] = __builtin_amdgcn_mfma_f32_32x32x16_bf16(
              af[mt], bb[nt], acc[mt][nt], 0, 0, 0);
    }
  }

  // epilogue: C/D col = lane&31, row = (reg&3) + 8*(reg>>2) + 4*(lane>>5)
#pragma unroll
  for (int mt = 0; mt < 2; ++mt) {
#pragma unroll
    for (int nt = 0; nt < 2; ++nt) {
#pragma unroll
      for (int rg = 0; rg < 16; ++rg) {
        int gm = m0 + wrow + mt * 32 + (rg & 3) + 8 * (rg >> 2) + 4 * l5;
        int gn = n0 + wcol + nt * 32 + l31;
        if (gm >= Mstore) continue;
        float v = acc[mt][nt][rg] * alpha;
        long ci = cofs + (long)gm * ldc + gn;
        if (flags & F_SIMSC)  v *= rs[gm] * cs[gn];
        if (flags & F_ROWSC)  v *= rs[gm];
        if (bias)             v += bias[(flags & F_BIASM) ? gm : gn];
        if (flags & F_RESID2) v += bf2f(residH[ci]) + bf2f(residL[ci]);
        if (flags & F_RELU)   v = fmaxf(v, 0.f);
        if (Cf) Cf[ci] = v;
        if (Cb) {
          u16 hv = f2bf(v);
          Cb[ci] = hv;
          if (Cb2) Cb2[ci] = f2bf(v - bf2f(hv));
        }
      }
    }
  }
}

// ---------------------------------------------------------------------------
__global__ __launch_bounds__(256)
void castbf_k(const float* __restrict__ in, u16* __restrict__ out, int n)
{
  int i = blockIdx.x * 256 + threadIdx.x;
  if (i < n) out[i] = f2bf(in[i]);
}

// all 7 weight matrices in one launch (layout matches wgt arena)
__global__ __launch_bounds__(256)
void castw_k(const float* w0, const float* w1, const float* w2,
             const float* w3, const float* w4, const float* w5,
             const float* w6, u16* __restrict__ dst)
{
  int i = blockIdx.x * 256 + threadIdx.x;
  const float* s; int off;
  if      (i < 262144)  { s = w0; off = 0; }
  else if (i < 1048576) { s = w1; off = 262144; }
  else if (i < 1310720) { s = w2; off = 1048576; }
  else if (i < 1835008) { s = w3; off = 1310720; }
  else if (i < 2359296) { s = w4; off = 1835008; }
  else if (i < 2883584) { s = w5; off = 2359296; }
  else                  { s = w6; off = 2883584; }
  dst[i] = f2bf(s[i - off]);
}

// x1 = LN(bf16 a + bf16 b) -> hi (in place over a ok) + lo
__global__ __launch_bounds__(256)
void ln1_k(const u16* __restrict__ a, const u16* __restrict__ b,
           const float* __restrict__ g, const float* __restrict__ be,
           u16* __restrict__ oh, u16* __restrict__ ol)
{
  long base = (long)blockIdx.x * 512;
  int t = threadIdx.x;
  float v0 = bf2f(a[base + t])       + bf2f(b[base + t]);
  float v1 = bf2f(a[base + t + 256]) + bf2f(b[base + t + 256]);
  __shared__ float red[4], red2[4];
  float s = wsum(v0 + v1);
  if ((t & 63) == 0) red[t >> 6] = s;
  __syncthreads();
  float mean = (red[0] + red[1] + red[2] + red[3]) * (1.f / 512.f);
  float c0 = v0 - mean, c1 = v1 - mean;
  float ss = wsum(c0 * c0 + c1 * c1);
  if ((t & 63) == 0) red2[t >> 6] = ss;
  __syncthreads();
  float var = (red2[0] + red2[1] + red2[2] + red2[3]) * (1.f / 512.f);
  float rstd = rsqrtf(var + 1e-5f);
  float o0 = c0 * rstd * g[t]       + be[t];
  float o1 = c1 * rstd * g[t + 256] + be[t + 256];
  u16 h0 = f2bf(o0), h1 = f2bf(o1);
  oh[base + t] = h0;       oh[base + t + 256] = h1;
  ol[base + t] = f2bf(o0 - bf2f(h0));
  ol[base + t + 256] = f2bf(o1 - bf2f(h1));
}

// x2 = LN((hi+lo) + bf16 b) -> bf16
__global__ __launch_bounds__(256)
void ln2_k(const u16* __restrict__ hi, const u16* __restrict__ lo,
           const u16* __restrict__ b, const float* __restrict__ g,
           const float* __restrict__ be, u16* __restrict__ ob)
{
  long base = (long)blockIdx.x * 512;
  int t = threadIdx.x;
  float v0 = bf2f(hi[base + t])       + bf2f(lo[base + t])       + bf2f(b[base + t]);
  float v1 = bf2f(hi[base + t + 256]) + bf2f(lo[base + t + 256]) + bf2f(b[base + t + 256]);
  __shared__ float red[4], red2[4];
  float s = wsum(v0 + v1);
  if ((t & 63) == 0) red[t >> 6] = s;
  __syncthreads();
  float mean = (red[0] + red[1] + red[2] + red[3]) * (1.f / 512.f);
  float c0 = v0 - mean, c1 = v1 - mean;
  float ss = wsum(c0 * c0 + c1 * c1);
  if ((t & 63) == 0) red2[t >> 6] = ss;
  __syncthreads();
  float var = (red2[0] + red2[1] + red2[2] + red2[3]) * (1.f / 512.f);
  float rstd = rsqrtf(var + 1e-5f);
  ob[base + t]       = f2bf(c0 * rstd * g[t]       + be[t]);
  ob[base + t + 256] = f2bf(c1 * rstd * g[t + 256] + be[t + 256]);
}

// invn[row] = 1/max(||hi+lo||, 1e-12)
__global__ __launch_bounds__(256)
void rownorm_k(const u16* __restrict__ hi, const u16* __restrict__ lo,
               float* __restrict__ invn)
{
  long base = (long)blockIdx.x * 512;
  int t = threadIdx.x;
  float v0 = bf2f(hi[base + t])       + bf2f(lo[base + t]);
  float v1 = bf2f(hi[base + t + 256]) + bf2f(lo[base + t + 256]);
  __shared__ float red[4];
  float s = wsum(v0 * v0 + v1 * v1);
  if ((t & 63) == 0) red[t >> 6] = s;
  __syncthreads();
  if (t == 0) {
    float tot = red[0] + red[1] + red[2] + red[3];
    invn[blockIdx.x] = 1.f / fmaxf(sqrtf(tot), 1e-12f);
  }
}

// in-place row softmax over 1024 bf16
__global__ __launch_bounds__(256)
void softmaxu_k(u16* __restrict__ sc)
{
  long row = blockIdx.x;
  u16* p = sc + row * 1024;
  int t = threadIdx.x;
  float v[4];
#pragma unroll
  for (int i = 0; i < 4; ++i) v[i] = bf2f(p[t + 256 * i]);
  __shared__ float redm[4], redsum[4];
  float m4 = fmaxf(fmaxf(v[0], v[1]), fmaxf(v[2], v[3]));
  float wm = wmaxf(m4);
  if ((t & 63) == 0) redm[t >> 6] = wm;
  __syncthreads();
  float MX = fmaxf(fmaxf(redm[0], redm[1]), fmaxf(redm[2], redm[3]));
  float s = 0.f;
#pragma unroll
  for (int i = 0; i < 4; ++i) { v[i] = __expf(v[i] - MX); s += v[i]; }
  float ws_ = wsum(s);
  if ((t & 63) == 0) redsum[t >> 6] = ws_;
  __syncthreads();
  float inv = 1.f / (redsum[0] + redsum[1] + redsum[2] + redsum[3]);
#pragma unroll
  for (int i = 0; i < 4; ++i) p[t + 256 * i] = f2bf(v[i] * inv);
}

// 64x64 tiled u16 transpose (used only for x1T)
__global__ __launch_bounds__(256)
void transp_k(const u16* __restrict__ in, u16* __restrict__ out,
              int inStride, int outStride, long sIn, long sOut)
{
  const int z = blockIdx.z;
  const u16* src = in + (long)z * sIn;
  u16* dst = out + (long)z * sOut;
  const int r0 = blockIdx.x * 64, c0 = blockIdx.y * 64;
  __shared__ u16 tile[64][66];
  const int t = threadIdx.x;
#pragma unroll
  for (int p = 0; p < 16; ++p) {
    int idx = p * 256 + t;
    int r = idx >> 6, c = idx & 63;
    tile[r][c] = src[(long)(r0 + r) * inStride + c0 + c];
  }
  __syncthreads();
#pragma unroll
  for (int p = 0; p < 16; ++p) {
    int idx = p * 256 + t;
    int c = idx >> 6, r = idx & 63;
    dst[(long)(c0 + c) * outStride + r0 + r] = tile[r][c];
  }
}

// per-row top-4 from bf16 sim, row cached in LDS (one HBM read per row).
__global__ __launch_bounds__(256)
void topk_k(const u16* __restrict__ sim, int* __restrict__ idx4)
{
  __shared__ float row[1024];
  __shared__ float bv[4];
  __shared__ int   bidx[4];
  long r = blockIdx.x;
  const u16* p = sim + r * 1024;
  int t = threadIdx.x;
  for (int i = t; i < 1024; i += 256) row[i] = bf2f(p[i]);
  __syncthreads();
  int c0 = -1, c1 = -1, c2 = -1, c3 = -1;
#pragma unroll
  for (int pass = 0; pass < 4; ++pass) {
    float best = -INFINITY;
    int bi = 1 << 30;
#pragma unroll
    for (int q = 0; q < 4; ++q) {
      int j = t + q * 256;
      if (j == c0 || j == c1 || j == c2 || j == c3) continue;
      float v = row[j];
      if (v > best || (v == best && j < bi)) { best = v; bi = j; }
    }
#pragma unroll
    for (int off = 32; off; off >>= 1) {
      float ov = __shfl_down(best, off);
      int   oi = __shfl_down(bi, off);
      if (ov > best || (ov == best && oi < bi)) { best = ov; bi = oi; }
    }
    if ((t & 63) == 0) { bv[t >> 6] = best; bidx[t >> 6] = bi; }
    __syncthreads();
    if (t == 0) {
      float bb = bv[0]; int ii = bidx[0];
#pragma unroll
      for (int w = 1; w < 4; ++w)
        if (bv[w] > bb || (bv[w] == bb && bidx[w] < ii)) { bb = bv[w]; ii = bidx[w]; }
      bidx[0] = ii;
    }
    __syncthreads();
    int sel = bidx[0];
    if (pass == 0) c0 = sel; else if (pass == 1) c1 = sel;
    else if (pass == 2) c2 = sel; else c3 = sel;
    __syncthreads();
  }
  if (t == 0) { int* q = idx4 + r * 4; q[0] = c0; q[1] = c1; q[2] = c2; q[3] = c3; }
}

// adjacency IN PLACE over bf16 sim + invcnt (chunk-local rows)
__global__ __launch_bounds__(256)
void adjbf_k(u16* __restrict__ simadj, const int* __restrict__ idx4,
             float* __restrict__ invcnt)
{
  long row = blockIdx.x;
  int b = (int)(row >> 10);
  int i = (int)(row & 1023);
  u16* prow = simadj + row * 1024;
  const int* my = idx4 + row * 4;
  int m0 = my[0], m1 = my[1], m2 = my[2], m3 = my[3];
  int t = threadIdx.x;
  float lsum = 0.f;
  for (int j = t; j < 1024; j += 256) {
    float v = bf2f(prow[j]);
    bool present = false;
    if (j != i) {
      present = (j == m0) | (j == m1) | (j == m2) | (j == m3);
      if (!present) {
        const int* oj = idx4 + (((long)b << 10) + j) * 4;
        present = (oj[0] == i) | (oj[1] == i) | (oj[2] == i) | (oj[3] == i);
      }
    }
    float a = present ? v : 0.f;
    prow[j] = present ? prow[j] : (u16)0;
    lsum += a;
  }
  __shared__ float red[4];
  float s = wsum(lsum);
  if ((t & 63) == 0) red[t >> 6] = s;
  __syncthreads();
  if (t == 0) {
    float tot = red[0] + red[1] + red[2] + red[3];
    invcnt[row] = 1.f / fmaxf(tot, 1.f);
  }
}

// pooled_bf[128][512]: rows<32 = mean_s x2_bf, rows>=32 = 0
__global__ __launch_bounds__(256)
void poolbf_k(const u16* __restrict__ x2, u16* __restrict__ pooled)
{
  int i = blockIdx.x * 256 + threadIdx.x;   // 0..65535
  int b = i >> 9, d = i & 511;
  float s = 0.f;
  if (b < 32) {
    const u16* p = x2 + ((long)b << 10) * 512 + d;
    for (int sdx = 0; sdx < 1024; ++sdx) s += bf2f(p[(long)sdx * 512]);
    s *= (1.f / 1024.f);
  }
  pooled[i] = f2bf(s);
}

// ---------------------------------------------------------------------------
static inline GSeg mkseg(const u16* A, const u16* B, int K, int lda, int ldb,
                         long sA = 0, long sB = 0, int hA = 0, int hB = 0)
{
  GSeg s; s.A = A; s.B = B; s.K = K; s.lda = lda; s.ldb = ldb;
  s.sA = sA; s.sB = sB; s.hA = hA; s.hB = hB; return s;
}

static inline void bgemm(hipStream_t st, GSeg s0, GSeg s1, GSeg s2,
    const float* bias, const u16* residH, const u16* residL,
    const float* rsc, const float* csc, float* Cf, u16* Cb, u16* Cb2,
    int M, int N, int ldc, long sC, int hC, int headBits, int sS,
    float alpha, int flags, int nz, int Mstore = -1)
{
  dim3 g(M / 128, N / 128, nz);
  bgemm_k<<<g, 256, 0, st>>>(s0, s1, s2, bias, residH, residL,
                             rsc, csc, Cf, Cb, Cb2, ldc, sC, hC, headBits,
                             sS, alpha, flags, Mstore < 0 ? M : Mstore);
}

extern "C" void kernel_launch(void* const* d_in, const int* in_sizes, int n_in,
                              void* d_out, int out_size, void* d_ws, size_t ws_size,
                              hipStream_t stream)
{
  (void)in_sizes; (void)n_in; (void)out_size;
  const float* x     = (const float*)d_in[0];
  const float* enc_w = (const float*)d_in[1];
  const float* enc_b = (const float*)d_in[2];
  const float* in_w  = (const float*)d_in[3];
  const float* in_b  = (const float*)d_in[4];
  const float* out_w = (const float*)d_in[5];
  const float* out_b = (const float*)d_in[6];
  const float* ln1_g = (const float*)d_in[7];
  const float* ln1_b = (const float*)d_in[8];
  const float* fw1   = (const float*)d_in[9];
  const float* fb1   = (const float*)d_in[10];
  const float* fw2   = (const float*)d_in[11];
  const float* fb2   = (const float*)d_in[12];
  const float* gc_w  = (const float*)d_in[13];
  const float* gc_b  = (const float*)d_in[14];
  const float* ln2_g = (const float*)d_in[15];
  const float* ln2_b = (const float*)d_in[16];
  const float* dec_w = (const float*)d_in[17];
  const float* dec_b = (const float*)d_in[18];
  float* out = (float*)d_out;

  // ---- arena ----
  char* base = (char*)d_ws;
  u16*  bf1  = (u16*)(base);                  // h_bf -> x1_hi (in place)
  u16*  lob  = (u16*)(base + 33554432);       // vT (attention) -> x1_lo
  u16*  bf2  = (u16*)(base + 67108864);       // ctx -> nsum -> x2
  u16*  wgt  = (u16*)(base + 100663296);      // bf16 weights
  float* invn    = (float*)(base + 106954752);
  float* invcnt  = (float*)(base + 107085824);
  u16*   pooledb = (u16*)(base + 107216896);
  int*   idx4    = (int*)(base + 107347968);
  char*  scr     = base + 107872256;          // 80MB scratch, phase-multiplexed
  const size_t need = 107872256 + 83886080;
  if (ws_size < need) return;

  u16* encw = wgt;
  u16* inw  = wgt + 262144;
  u16* outw = wgt + 1048576;
  u16* fw1b = wgt + 1310720;
  u16* fw2b = wgt + 1835008;
  u16* gcwb = wgt + 2359296;
  u16* decw = wgt + 2883584;

  const int Mtok = 32768;
  GSeg Z = mkseg(nullptr, nullptr, 0, 0, 0);

  // ---- casts ----
  u16* xbf = (u16*)scr;
  castbf_k<<<65536, 256, 0, stream>>>(x, xbf, 16777216);
  castw_k<<<12288, 256, 0, stream>>>(enc_w, in_w, out_w, fw1, fw2, gc_w, dec_w, wgt);

  // 1. h_bf = relu(x @ enc_w^T + enc_b)
  bgemm(stream, mkseg(xbf, encw, 512, 512, 512), Z, Z,
        enc_b, nullptr, nullptr, nullptr, nullptr, nullptr, bf1, nullptr,
        Mtok, 512, 512, 0, 0, 0, 0, 1.f, F_RELU, 1);

  // 2. vT = Wv @ h^T  (A/B-swapped GEMM, per-row bias) -> lob [512][32768]
  bgemm(stream, mkseg(inw + 524288, bf1, 512, 512, 512), Z, Z,
        in_b + 1024, nullptr, nullptr, nullptr, nullptr, nullptr,
        lob, nullptr, 512, Mtok, Mtok, 0, 0, 0, 0, 1.f, F_BIASM, 1);

  // 3. attention: 4 chunks x 8 batches, heads folded into z (z=16)
  for (int c = 0; c < 4; ++c) {
    long row0 = (long)c * 8192;
    u16* qkc = (u16*)scr;                         // 8192x1024 u16 (16MB)
    u16* sco = (u16*)(scr + 16777216);            // 16 x 1024x1024 u16 (32MB)
    bgemm(stream, mkseg(bf1 + row0 * 512, inw, 512, 512, 512), Z, Z,
          in_b, nullptr, nullptr, nullptr, nullptr, nullptr, qkc, nullptr,
          8192, 1024, 1024, 0, 0, 0, 0, 1.f, 0, 1);
    // scores[z=16] = 1/16 * Q @ K^T  -> bf16
    bgemm(stream, mkseg(qkc, qkc + 512, 256, 1024, 1024,
                        1048576, 1048576, 256, 256), Z, Z,
          nullptr, nullptr, nullptr, nullptr, nullptr, nullptr, sco, nullptr,
          1024, 1024, 1024, 2097152, 1048576, 1, 0, 0.0625f, 0, 16);
    softmaxu_k<<<16384, 256, 0, stream>>>(sco);
    // ctx = P @ V   (B = vT rows d, per-batch col offset, per-head row offset)
    bgemm(stream, mkseg(sco, lob + (row0 >> 10) * 1024, 1024, 1024, Mtok,
                        2097152, 1024, 1048576, 8388608), Z, Z,
          nullptr, nullptr, nullptr, nullptr, nullptr, nullptr,
          bf2 + row0 * 512, nullptr,
          1024, 256, 512, 524288, 256, 1, 0, 1.f, 0, 16);
  }

  // 4. attn_out -> bf16
  u16* aoc = (u16*)scr;                           // 32MB
  bgemm(stream, mkseg(bf2, outw, 512, 512, 512), Z, Z,
        out_b, nullptr, nullptr, nullptr, nullptr, nullptr, aoc, nullptr,
        Mtok, 512, 512, 0, 0, 0, 0, 1.f, 0, 1);

  // 5. x1 = LN(h + attn_out) -> hi (in place) + lo (lob; vT consumed)
  ln1_k<<<Mtok, 256, 0, stream>>>(bf1, aoc, ln1_g, ln1_b, bf1, lob);

  // 6+7. FFN
  u16* mid = (u16*)scr;                           // 64MB
  bgemm(stream, mkseg(bf1, fw1b, 512, 512, 512), Z, Z,
        fb1, nullptr, nullptr, nullptr, nullptr, nullptr, mid, nullptr,
        Mtok, 1024, 1024, 0, 0, 0, 0, 1.f, F_RELU, 1);
  bgemm(stream, mkseg(mid, fw2b, 1024, 1024, 1024), Z, Z,
        fb2, bf1, lob, nullptr, nullptr, nullptr, bf1, lob,
        Mtok, 512, 512, 0, 0, 0, 0, 1.f, F_RESID2, 1);

  // 8. row norms
  rownorm_k<<<Mtok, 256, 0, stream>>>(bf1, lob, invn);

  // 9-12. graph: x1T once, then 2 chunks x 16 batches; sim bf16 in-place adj
  u16* simadj = (u16*)scr;                        // 32MB (16 x 1024x1024 u16)
  u16* x1T    = (u16*)(scr + 33554432);           // 32MB (all 32 batches)
  transp_k<<<dim3(16, 8, 32), 256, 0, stream>>>(bf1, x1T, 512, 1024,
                                                524288, 524288);
  for (int g = 0; g < 2; ++g) {
    long row0 = (long)g * 16384;
    // sim = (hi.hi^T) * invn_i * invn_j  -> bf16
    bgemm(stream,
          mkseg(bf1 + row0 * 512, bf1 + row0 * 512, 512, 512, 512, 524288, 524288),
          Z, Z, nullptr, nullptr, nullptr, invn + row0, invn + row0,
          nullptr, simadj, nullptr,
          1024, 1024, 1024, 1048576, 0, 0, 1024, 1.f, F_SIMSC, 16);
    topk_k<<<16384, 256, 0, stream>>>(simadj, idx4 + row0 * 4);
    adjbf_k<<<16384, 256, 0, stream>>>(simadj, idx4 + row0 * 4, invcnt + row0);
    // nsum = (adj @ x1) * invcnt
    bgemm(stream, mkseg(simadj, x1T + row0 * 512, 1024, 1024, 1024,
                        1048576, 524288), Z, Z,
          nullptr, nullptr, nullptr, invcnt + row0, nullptr, nullptr,
          bf2 + row0 * 512, nullptr,
          1024, 512, 512, 524288, 0, 0, 1024, 1.f, F_ROWSC, 16);
  }

  // 13/14. gcout = x1_hi @ gcW1^T + nsum @ gcW2^T + gc_b  (2-seg) -> bf16
  u16* gch = (u16*)scr;                           // 32MB
  bgemm(stream, mkseg(bf1, gcwb, 512, 512, 1024),
        mkseg(bf2, gcwb + 512, 512, 512, 1024), Z,
        gc_b, nullptr, nullptr, nullptr, nullptr, nullptr, gch, nullptr,
        Mtok, 512, 512, 0, 0, 0, 0, 1.f, 0, 1);

  // 15. x2 = LN(x1 + gcout) -> bf16 (over bf2; nsum consumed)
  ln2_k<<<Mtok, 256, 0, stream>>>(bf1, lob, gch, ln2_g, ln2_b, bf2);

  // 16+17. pool + decoder
  poolbf_k<<<256, 256, 0, stream>>>(bf2, pooledb);
  bgemm(stream, mkseg(pooledb, decw, 512, 512, 512), Z, Z,
        dec_b, nullptr, nullptr, nullptr, nullptr, out, nullptr, nullptr,
        128, 512, 512, 0, 0, 0, 0, 1.f, 0, 1, 32);
}

// Round 11
// 1482.181 us; speedup vs baseline: 1.0115x; 1.0115x over previous
//
#include <hip/hip_runtime.h>
#include <hip/hip_bf16.h>
#include <math.h>

typedef unsigned short u16;
typedef unsigned int u32;
typedef __attribute__((ext_vector_type(8))) short bfrag;     // 8 bf16 (4 VGPR)
typedef __attribute__((ext_vector_type(16))) float facc16;   // 16 fp32 acc
typedef const __attribute__((address_space(1))) void* gaddr_t;
typedef __attribute__((address_space(3))) void* laddr_t;

#define F_RELU   1
#define F_ROWSC  4   // *= rsc[m]
#define F_SIMSC  8   // *= rsc[m]*csc[n]
#define F_RESID2 32  // += bf16 residH + residL
#define F_BIASM  64  // bias indexed by gm (row) instead of gn

__device__ __forceinline__ u16 f2bf(float f) {
  __hip_bfloat16 h = __float2bfloat16(f);
  return *reinterpret_cast<u16*>(&h);
}
__device__ __forceinline__ float bf2f(u16 u) {
  __hip_bfloat16 h = *reinterpret_cast<__hip_bfloat16*>(&u);
  return __bfloat162float(h);
}
// packed bf16 pair helpers (low u16 = first element)
__device__ __forceinline__ float2 unpack2(u32 u) {
  float2 r;
  r.x = __uint_as_float(u << 16);
  r.y = __uint_as_float(u & 0xffff0000u);
  return r;
}
__device__ __forceinline__ u32 pack2(float x, float y) {
  return (u32)f2bf(x) | ((u32)f2bf(y) << 16);
}
__device__ __forceinline__ float wsum(float v) {
#pragma unroll
  for (int o = 32; o; o >>= 1) v += __shfl_xor(v, o);
  return v;
}
__device__ __forceinline__ float wmaxf(float v) {
#pragma unroll
  for (int o = 32; o; o >>= 1) v = fmaxf(v, __shfl_xor(v, o));
  return v;
}

struct GSeg {
  const u16* A; const u16* B;
  long sA, sB;          // per-z strides
  int lda, ldb, K;      // K % 64 == 0
  int hA, hB;           // per-head offsets (headBits mode)
};

// ---------------------------------------------------------------------------
// bf16 MFMA GEMM, up to 3 K-segments (R9 engine — frozen):
// 256 thr = 4 waves; tile 128x128; BK=64; dbuf LDS 2x32KB; 32x32x16 MFMA.
// [R10 post-mortem: XCD swizzle cut FETCH 103->27MB but dur 115->128us —
//  engine is latency/structure-bound, invariant to cache locality. Frozen.]
// ---------------------------------------------------------------------------
__global__ __launch_bounds__(256)
void bgemm_k(GSeg s0, GSeg s1, GSeg s2,
             const float* __restrict__ bias,
             const u16* __restrict__ residH, const u16* __restrict__ residL,
             const float* __restrict__ rsc, const float* __restrict__ csc,
             float* __restrict__ Cf, u16* __restrict__ Cb, u16* __restrict__ Cb2,
             int ldc, long sC, int hC, int headBits, int sS,
             float alpha, int flags, int Mstore)
{
  const int zAll = blockIdx.z;
  const int hIdx = headBits ? (zAll & 1) : 0;
  const int z    = headBits ? (zAll >> 1) : zAll;
  const long cofs = (long)z * sC + (long)hIdx * hC;
  const float* rs = rsc ? rsc + (long)z * sS : nullptr;
  const float* cs = csc ? csc + (long)z * sS : nullptr;

  __shared__ u16 As[2][128 * 64];
  __shared__ u16 Bs[2][128 * 64];

  const int tid  = threadIdx.x;
  const int wave = tid >> 6, lane = tid & 63;
  const int m0 = blockIdx.x * 128, n0 = blockIdx.y * 128;
  const int wrow = (wave >> 1) * 64, wcol = (wave & 1) * 64;

  const u16* ApS[3]; const u16* BpS[3]; int ldaS[3], ldbS[3];
  ApS[0] = s0.A + (long)z * s0.sA + (long)hIdx * s0.hA;
  BpS[0] = s0.B + (long)z * s0.sB + (long)hIdx * s0.hB;
  ldaS[0] = s0.lda; ldbS[0] = s0.ldb;
  ApS[1] = s1.A ? s1.A + (long)z * s1.sA + (long)hIdx * s1.hA : nullptr;
  BpS[1] = s1.B ? s1.B + (long)z * s1.sB + (long)hIdx * s1.hB : nullptr;
  ldaS[1] = s1.lda; ldbS[1] = s1.ldb;
  ApS[2] = s2.A ? s2.A + (long)z * s2.sA + (long)hIdx * s2.hA : nullptr;
  BpS[2] = s2.B ? s2.B + (long)z * s2.sB + (long)hIdx * s2.hB : nullptr;
  ldaS[2] = s2.lda; ldbS[2] = s2.ldb;
  const int n0i = s0.K >> 6, n1i = n0i + (s1.K >> 6);
  const int nIt = n1i + (s2.K >> 6);

  const int lrow = lane >> 3;          // 0..7
  const int lgrp = lane & 7;           // 0..7

  facc16 acc[2][2];
#pragma unroll
  for (int i = 0; i < 2; ++i)
#pragma unroll
    for (int j = 0; j < 2; ++j) acc[i][j] = (facc16)(0.f);

  const int l31 = lane & 31, l5 = lane >> 5;

  auto stage = [&](int buf, int it) {
    int sidx, base;
    if (it < n0i)      { sidx = 0; base = 0; }
    else if (it < n1i) { sidx = 1; base = n0i; }
    else               { sidx = 2; base = n1i; }
    const int k0 = (it - base) << 6;
    const u16* Ab = ApS[sidx];
    const u16* Bb = BpS[sidx];
    const int la = ldaS[sidx], lb = ldbS[sidx];
#pragma unroll
    for (int ss = 0; ss < 4; ++ss) {
      int rloc = wave * 32 + ss * 8;
      int row  = rloc + lrow;
      int g    = lgrp ^ ((row >> 1) & 7);
      __builtin_amdgcn_global_load_lds(
          (gaddr_t)(const void*)(Ab + (long)(m0 + row) * la + k0 + g * 8),
          (laddr_t)(As[buf] + rloc * 64), 16, 0, 0);
      __builtin_amdgcn_global_load_lds(
          (gaddr_t)(const void*)(Bb + (long)(n0 + row) * lb + k0 + g * 8),
          (laddr_t)(Bs[buf] + rloc * 64), 16, 0, 0);
    }
  };

  stage(0, 0);
  for (int it = 0; it < nIt; ++it) {
    const int buf = it & 1;
    __syncthreads();                      // drains glds; buf ready
    if (it + 1 < nIt) stage(buf ^ 1, it + 1);

#pragma unroll
    for (int ks = 0; ks < 4; ++ks) {      // K=16 per MFMA step
      const int gg = ks * 2 + l5;
      bfrag af[2], bb[2];
#pragma unroll
      for (int mt = 0; mt < 2; ++mt) {
        int r = wrow + mt * 32 + l31;
        int slot = gg ^ ((r >> 1) & 7);
        af[mt] = *(const bfrag*)&As[buf][r * 64 + slot * 8];
      }
#pragma unroll
      for (int nt = 0; nt < 2; ++nt) {
        int r = wcol + nt * 32 + l31;
        int slot = gg ^ ((r >> 1) & 7);
        bb[nt] = *(const bfrag*)&Bs[buf][r * 64 + slot * 8];
      }
#pragma unroll
      for (int mt = 0; mt < 2; ++mt)
#pragma unroll
        for (int nt = 0; nt < 2; ++nt)
          acc[mt][nt] = __builtin_amdgcn_mfma_f32_32x32x16_bf16(
              af[mt], bb[nt], acc[mt][nt], 0, 0, 0);
    }
  }

  // epilogue: C/D col = lane&31, row = (reg&3) + 8*(reg>>2) + 4*(lane>>5)
#pragma unroll
  for (int mt = 0; mt < 2; ++mt) {
#pragma unroll
    for (int nt = 0; nt < 2; ++nt) {
#pragma unroll
      for (int rg = 0; rg < 16; ++rg) {
        int gm = m0 + wrow + mt * 32 + (rg & 3) + 8 * (rg >> 2) + 4 * l5;
        int gn = n0 + wcol + nt * 32 + l31;
        if (gm >= Mstore) continue;
        float v = acc[mt][nt][rg] * alpha;
        long ci = cofs + (long)gm * ldc + gn;
        if (flags & F_SIMSC)  v *= rs[gm] * cs[gn];
        if (flags & F_ROWSC)  v *= rs[gm];
        if (bias)             v += bias[(flags & F_BIASM) ? gm : gn];
        if (flags & F_RESID2) v += bf2f(residH[ci]) + bf2f(residL[ci]);
        if (flags & F_RELU)   v = fmaxf(v, 0.f);
        if (Cf) Cf[ci] = v;
        if (Cb) {
          u16 hv = f2bf(v);
          Cb[ci] = hv;
          if (Cb2) Cb2[ci] = f2bf(v - bf2f(hv));
        }
      }
    }
  }
}

// ---------------------------------------------------------------------------
// x (float4) -> bf16x4, n%4==0
__global__ __launch_bounds__(256)
void castbf4_k(const float* __restrict__ in, u16* __restrict__ out, int n4)
{
  int i = blockIdx.x * 256 + threadIdx.x;
  if (i >= n4) return;
  float4 v = ((const float4*)in)[i];
  uint2 o;
  o.x = pack2(v.x, v.y);
  o.y = pack2(v.z, v.w);
  ((uint2*)out)[i] = o;
}

// all 7 weight matrices, 4 elems/thread (all segment bounds %4==0)
__global__ __launch_bounds__(256)
void castw4_k(const float* w0, const float* w1, const float* w2,
              const float* w3, const float* w4, const float* w5,
              const float* w6, u16* __restrict__ dst)
{
  int i = blockIdx.x * 256 + threadIdx.x;     // 786432 quads
  int e = i * 4;
  const float* s; int off;
  if      (e < 1048576)  { s = (e < 262144) ? w0 : w1; off = (e < 262144) ? 0 : 262144; }
  else if (e < 1835008)  { s = (e < 1310720) ? w2 : w3; off = (e < 1310720) ? 1048576 : 1310720; }
  else if (e < 2883584)  { s = (e < 2359296) ? w4 : w5; off = (e < 2359296) ? 1835008 : 2359296; }
  else                   { s = w6; off = 2883584; }
  float4 v = *(const float4*)(s + (e - off));
  uint2 o;
  o.x = pack2(v.x, v.y);
  o.y = pack2(v.z, v.w);
  ((uint2*)dst)[i] = o;
}

// x1 = LN(bf16 a + bf16 b) -> hi (in place over a ok) + lo. 2 elems/thread.
__global__ __launch_bounds__(256)
void ln1_k(const u16* __restrict__ a, const u16* __restrict__ b,
           const float* __restrict__ g, const float* __restrict__ be,
           u16* __restrict__ oh, u16* __restrict__ ol)
{
  long base = (long)blockIdx.x * 256;         // in uints
  int t = threadIdx.x;
  float2 fa = unpack2(((const u32*)a)[base + t]);
  float2 fb = unpack2(((const u32*)b)[base + t]);
  float v0 = fa.x + fb.x, v1 = fa.y + fb.y;
  __shared__ float red[4], red2[4];
  float s = wsum(v0 + v1);
  if ((t & 63) == 0) red[t >> 6] = s;
  __syncthreads();
  float mean = (red[0] + red[1] + red[2] + red[3]) * (1.f / 512.f);
  float c0 = v0 - mean, c1 = v1 - mean;
  float ss = wsum(c0 * c0 + c1 * c1);
  if ((t & 63) == 0) red2[t >> 6] = ss;
  __syncthreads();
  float var = (red2[0] + red2[1] + red2[2] + red2[3]) * (1.f / 512.f);
  float rstd = rsqrtf(var + 1e-5f);
  float2 gg = ((const float2*)g)[t];
  float2 bb = ((const float2*)be)[t];
  float o0 = c0 * rstd * gg.x + bb.x;
  float o1 = c1 * rstd * gg.y + bb.y;
  u16 h0 = f2bf(o0), h1 = f2bf(o1);
  ((u32*)oh)[base + t] = (u32)h0 | ((u32)h1 << 16);
  ((u32*)ol)[base + t] = pack2(o0 - bf2f(h0), o1 - bf2f(h1));
}

// x2 = LN((hi+lo) + bf16 b) -> bf16. 2 elems/thread.
__global__ __launch_bounds__(256)
void ln2_k(const u16* __restrict__ hi, const u16* __restrict__ lo,
           const u16* __restrict__ b, const float* __restrict__ g,
           const float* __restrict__ be, u16* __restrict__ ob)
{
  long base = (long)blockIdx.x * 256;
  int t = threadIdx.x;
  float2 fh = unpack2(((const u32*)hi)[base + t]);
  float2 fl = unpack2(((const u32*)lo)[base + t]);
  float2 fb = unpack2(((const u32*)b)[base + t]);
  float v0 = fh.x + fl.x + fb.x, v1 = fh.y + fl.y + fb.y;
  __shared__ float red[4], red2[4];
  float s = wsum(v0 + v1);
  if ((t & 63) == 0) red[t >> 6] = s;
  __syncthreads();
  float mean = (red[0] + red[1] + red[2] + red[3]) * (1.f / 512.f);
  float c0 = v0 - mean, c1 = v1 - mean;
  float ss = wsum(c0 * c0 + c1 * c1);
  if ((t & 63) == 0) red2[t >> 6] = ss;
  __syncthreads();
  float var = (red2[0] + red2[1] + red2[2] + red2[3]) * (1.f / 512.f);
  float rstd = rsqrtf(var + 1e-5f);
  float2 gg = ((const float2*)g)[t];
  float2 bb = ((const float2*)be)[t];
  ((u32*)ob)[base + t] = pack2(c0 * rstd * gg.x + bb.x,
                               c1 * rstd * gg.y + bb.y);
}

// invn[row] = 1/max(||hi+lo||, 1e-12). 2 elems/thread.
__global__ __launch_bounds__(256)
void rownorm_k(const u16* __restrict__ hi, const u16* __restrict__ lo,
               float* __restrict__ invn)
{
  long base = (long)blockIdx.x * 256;
  int t = threadIdx.x;
  float2 fh = unpack2(((const u32*)hi)[base + t]);
  float2 fl = unpack2(((const u32*)lo)[base + t]);
  float v0 = fh.x + fl.x, v1 = fh.y + fl.y;
  __shared__ float red[4];
  float s = wsum(v0 * v0 + v1 * v1);
  if ((t & 63) == 0) red[t >> 6] = s;
  __syncthreads();
  if (t == 0) {
    float tot = red[0] + red[1] + red[2] + red[3];
    invn[blockIdx.x] = 1.f / fmaxf(sqrtf(tot), 1e-12f);
  }
}

// in-place row softmax over 1024 bf16. 4 elems/thread (uint2).
__global__ __launch_bounds__(256)
void softmaxu_k(u16* __restrict__ sc)
{
  long row = blockIdx.x;
  uint2* p = (uint2*)(sc + row * 1024) + threadIdx.x;
  int t = threadIdx.x;
  uint2 u = *p;
  float2 ab = unpack2(u.x), cd = unpack2(u.y);
  float v[4] = {ab.x, ab.y, cd.x, cd.y};
  __shared__ float redm[4], redsum[4];
  float m4 = fmaxf(fmaxf(v[0], v[1]), fmaxf(v[2], v[3]));
  float wm = wmaxf(m4);
  if ((t & 63) == 0) redm[t >> 6] = wm;
  __syncthreads();
  float MX = fmaxf(fmaxf(redm[0], redm[1]), fmaxf(redm[2], redm[3]));
  float s = 0.f;
#pragma unroll
  for (int i = 0; i < 4; ++i) { v[i] = __expf(v[i] - MX); s += v[i]; }
  float ws_ = wsum(s);
  if ((t & 63) == 0) redsum[t >> 6] = ws_;
  __syncthreads();
  float inv = 1.f / (redsum[0] + redsum[1] + redsum[2] + redsum[3]);
  u.x = pack2(v[0] * inv, v[1] * inv);
  u.y = pack2(v[2] * inv, v[3] * inv);
  *p = u;
}

// 64x64 tiled u16 transpose (used only for x1T)
__global__ __launch_bounds__(256)
void transp_k(const u16* __restrict__ in, u16* __restrict__ out,
              int inStride, int outStride, long sIn, long sOut)
{
  const int z = blockIdx.z;
  const u16* src = in + (long)z * sIn;
  u16* dst = out + (long)z * sOut;
  const int r0 = blockIdx.x * 64, c0 = blockIdx.y * 64;
  __shared__ u16 tile[64][66];
  const int t = threadIdx.x;
#pragma unroll
  for (int p = 0; p < 16; ++p) {
    int idx = p * 256 + t;
    int r = idx >> 6, c = idx & 63;
    tile[r][c] = src[(long)(r0 + r) * inStride + c0 + c];
  }
  __syncthreads();
#pragma unroll
  for (int p = 0; p < 16; ++p) {
    int idx = p * 256 + t;
    int c = idx >> 6, r = idx & 63;
    dst[(long)(c0 + c) * outStride + r0 + r] = tile[r][c];
  }
}

// per-row top-4 from bf16 sim, row cached in LDS (uint2 staging).
__global__ __launch_bounds__(256)
void topk_k(const u16* __restrict__ sim, int* __restrict__ idx4)
{
  __shared__ float row[1024];
  __shared__ float bv[4];
  __shared__ int   bidx[4];
  long r = blockIdx.x;
  int t = threadIdx.x;
  {
    uint2 u = ((const uint2*)(sim + r * 1024))[t];
    float2 ab = unpack2(u.x), cd = unpack2(u.y);
    *(float4*)&row[4 * t] = make_float4(ab.x, ab.y, cd.x, cd.y);
  }
  __syncthreads();
  int c0 = -1, c1 = -1, c2 = -1, c3 = -1;
#pragma unroll
  for (int pass = 0; pass < 4; ++pass) {
    float best = -INFINITY;
    int bi = 1 << 30;
#pragma unroll
    for (int q = 0; q < 4; ++q) {
      int j = t + q * 256;
      if (j == c0 || j == c1 || j == c2 || j == c3) continue;
      float v = row[j];
      if (v > best || (v == best && j < bi)) { best = v; bi = j; }
    }
#pragma unroll
    for (int off = 32; off; off >>= 1) {
      float ov = __shfl_down(best, off);
      int   oi = __shfl_down(bi, off);
      if (ov > best || (ov == best && oi < bi)) { best = ov; bi = oi; }
    }
    if ((t & 63) == 0) { bv[t >> 6] = best; bidx[t >> 6] = bi; }
    __syncthreads();
    if (t == 0) {
      float bb = bv[0]; int ii = bidx[0];
#pragma unroll
      for (int w = 1; w < 4; ++w)
        if (bv[w] > bb || (bv[w] == bb && bidx[w] < ii)) { bb = bv[w]; ii = bidx[w]; }
      bidx[0] = ii;
    }
    __syncthreads();
    int sel = bidx[0];
    if (pass == 0) c0 = sel; else if (pass == 1) c1 = sel;
    else if (pass == 2) c2 = sel; else c3 = sel;
    __syncthreads();
  }
  if (t == 0) { int* q = idx4 + r * 4; q[0] = c0; q[1] = c1; q[2] = c2; q[3] = c3; }
}

// adjacency IN PLACE over bf16 sim + invcnt; 4 consecutive j per thread.
__global__ __launch_bounds__(256)
void adjbf_k(u16* __restrict__ simadj, const int* __restrict__ idx4,
             float* __restrict__ invcnt)
{
  long row = blockIdx.x;
  int b = (int)(row >> 10);
  int i = (int)(row & 1023);
  uint2* prow2 = (uint2*)(simadj + row * 1024);
  const int* my = idx4 + row * 4;
  int m0 = my[0], m1 = my[1], m2 = my[2], m3 = my[3];
  int t = threadIdx.x;
  uint2 u = prow2[t];
  float2 ab = unpack2(u.x), cd = unpack2(u.y);
  float v[4] = {ab.x, ab.y, cd.x, cd.y};
  u16 h[4];
  h[0] = (u16)(u.x & 0xffff); h[1] = (u16)(u.x >> 16);
  h[2] = (u16)(u.y & 0xffff); h[3] = (u16)(u.y >> 16);
  float lsum = 0.f;
#pragma unroll
  for (int q = 0; q < 4; ++q) {
    int j = 4 * t + q;
    bool present = false;
    if (j != i) {
      present = (j == m0) | (j == m1) | (j == m2) | (j == m3);
      if (!present) {
        const int* oj = idx4 + (((long)b << 10) + j) * 4;
        present = (oj[0] == i) | (oj[1] == i) | (oj[2] == i) | (oj[3] == i);
      }
    }
    if (present) lsum += v[q]; else h[q] = 0;
  }
  u.x = (u32)h[0] | ((u32)h[1] << 16);
  u.y = (u32)h[2] | ((u32)h[3] << 16);
  prow2[t] = u;
  __shared__ float red[4];
  float s = wsum(lsum);
  if ((t & 63) == 0) red[t >> 6] = s;
  __syncthreads();
  if (t == 0) {
    float tot = red[0] + red[1] + red[2] + red[3];
    invcnt[row] = 1.f / fmaxf(tot, 1.f);
  }
}

// pooled_bf[128][512]: rows<32 = mean_s x2_bf, rows>=32 = 0. 2 cols/thread.
__global__ __launch_bounds__(256)
void poolbf_k(const u16* __restrict__ x2, u16* __restrict__ pooled)
{
  int i = blockIdx.x * 256 + threadIdx.x;   // 0..32767
  int b = i >> 8, d2 = i & 255;
  float sx = 0.f, sy = 0.f;
  if (b < 32) {
    const u32* p = (const u32*)x2 + ((long)b << 10) * 256 + d2;
    for (int sdx = 0; sdx < 1024; ++sdx) {
      float2 f = unpack2(p[(long)sdx * 256]);
      sx += f.x; sy += f.y;
    }
    sx *= (1.f / 1024.f); sy *= (1.f / 1024.f);
  }
  ((u32*)pooled)[i] = pack2(sx, sy);
}

// ---------------------------------------------------------------------------
static inline GSeg mkseg(const u16* A, const u16* B, int K, int lda, int ldb,
                         long sA = 0, long sB = 0, int hA = 0, int hB = 0)
{
  GSeg s; s.A = A; s.B = B; s.K = K; s.lda = lda; s.ldb = ldb;
  s.sA = sA; s.sB = sB; s.hA = hA; s.hB = hB; return s;
}

static inline void bgemm(hipStream_t st, GSeg s0, GSeg s1, GSeg s2,
    const float* bias, const u16* residH, const u16* residL,
    const float* rsc, const float* csc, float* Cf, u16* Cb, u16* Cb2,
    int M, int N, int ldc, long sC, int hC, int headBits, int sS,
    float alpha, int flags, int nz, int Mstore = -1)
{
  dim3 g(M / 128, N / 128, nz);
  bgemm_k<<<g, 256, 0, st>>>(s0, s1, s2, bias, residH, residL,
                             rsc, csc, Cf, Cb, Cb2, ldc, sC, hC, headBits,
                             sS, alpha, flags, Mstore < 0 ? M : Mstore);
}

extern "C" void kernel_launch(void* const* d_in, const int* in_sizes, int n_in,
                              void* d_out, int out_size, void* d_ws, size_t ws_size,
                              hipStream_t stream)
{
  (void)in_sizes; (void)n_in; (void)out_size;
  const float* x     = (const float*)d_in[0];
  const float* enc_w = (const float*)d_in[1];
  const float* enc_b = (const float*)d_in[2];
  const float* in_w  = (const float*)d_in[3];
  const float* in_b  = (const float*)d_in[4];
  const float* out_w = (const float*)d_in[5];
  const float* out_b = (const float*)d_in[6];
  const float* ln1_g = (const float*)d_in[7];
  const float* ln1_b = (const float*)d_in[8];
  const float* fw1   = (const float*)d_in[9];
  const float* fb1   = (const float*)d_in[10];
  const float* fw2   = (const float*)d_in[11];
  const float* fb2   = (const float*)d_in[12];
  const float* gc_w  = (const float*)d_in[13];
  const float* gc_b  = (const float*)d_in[14];
  const float* ln2_g = (const float*)d_in[15];
  const float* ln2_b = (const float*)d_in[16];
  const float* dec_w = (const float*)d_in[17];
  const float* dec_b = (const float*)d_in[18];
  float* out = (float*)d_out;

  // ---- arena ----
  char* base = (char*)d_ws;
  u16*  bf1  = (u16*)(base);                  // h_bf -> x1_hi (in place)
  u16*  lob  = (u16*)(base + 33554432);       // vT (attention) -> x1_lo
  u16*  bf2  = (u16*)(base + 67108864);       // ctx -> nsum -> x2
  u16*  wgt  = (u16*)(base + 100663296);      // bf16 weights
  float* invn    = (float*)(base + 106954752);
  float* invcnt  = (float*)(base + 107085824);
  u16*   pooledb = (u16*)(base + 107216896);
  int*   idx4    = (int*)(base + 107347968);
  char*  scr     = base + 107872256;          // 80MB scratch, phase-multiplexed
  const size_t need = 107872256 + 83886080;
  if (ws_size < need) return;

  u16* encw = wgt;
  u16* inw  = wgt + 262144;
  u16* outw = wgt + 1048576;
  u16* fw1b = wgt + 1310720;
  u16* fw2b = wgt + 1835008;
  u16* gcwb = wgt + 2359296;
  u16* decw = wgt + 2883584;

  const int Mtok = 32768;
  GSeg Z = mkseg(nullptr, nullptr, 0, 0, 0);

  // ---- casts (vectorized) ----
  u16* xbf = (u16*)scr;
  castbf4_k<<<16384, 256, 0, stream>>>(x, xbf, 4194304);
  castw4_k<<<3072, 256, 0, stream>>>(enc_w, in_w, out_w, fw1, fw2, gc_w, dec_w, wgt);

  // 1. h_bf = relu(x @ enc_w^T + enc_b)
  bgemm(stream, mkseg(xbf, encw, 512, 512, 512), Z, Z,
        enc_b, nullptr, nullptr, nullptr, nullptr, nullptr, bf1, nullptr,
        Mtok, 512, 512, 0, 0, 0, 0, 1.f, F_RELU, 1);

  // 2. vT = Wv @ h^T  (A/B-swapped GEMM, per-row bias) -> lob [512][32768]
  bgemm(stream, mkseg(inw + 524288, bf1, 512, 512, 512), Z, Z,
        in_b + 1024, nullptr, nullptr, nullptr, nullptr, nullptr,
        lob, nullptr, 512, Mtok, Mtok, 0, 0, 0, 0, 1.f, F_BIASM, 1);

  // 3. attention: 4 chunks x 8 batches, heads folded into z (z=16)
  for (int c = 0; c < 4; ++c) {
    long row0 = (long)c * 8192;
    u16* qkc = (u16*)scr;                         // 8192x1024 u16 (16MB)
    u16* sco = (u16*)(scr + 16777216);            // 16 x 1024x1024 u16 (32MB)
    bgemm(stream, mkseg(bf1 + row0 * 512, inw, 512, 512, 512), Z, Z,
          in_b, nullptr, nullptr, nullptr, nullptr, nullptr, qkc, nullptr,
          8192, 1024, 1024, 0, 0, 0, 0, 1.f, 0, 1);
    // scores[z=16] = 1/16 * Q @ K^T  -> bf16
    bgemm(stream, mkseg(qkc, qkc + 512, 256, 1024, 1024,
                        1048576, 1048576, 256, 256), Z, Z,
          nullptr, nullptr, nullptr, nullptr, nullptr, nullptr, sco, nullptr,
          1024, 1024, 1024, 2097152, 1048576, 1, 0, 0.0625f, 0, 16);
    softmaxu_k<<<16384, 256, 0, stream>>>(sco);
    // ctx = P @ V   (B = vT rows d, per-batch col offset, per-head row offset)
    bgemm(stream, mkseg(sco, lob + (row0 >> 10) * 1024, 1024, 1024, Mtok,
                        2097152, 1024, 1048576, 8388608), Z, Z,
          nullptr, nullptr, nullptr, nullptr, nullptr, nullptr,
          bf2 + row0 * 512, nullptr,
          1024, 256, 512, 524288, 256, 1, 0, 1.f, 0, 16);
  }

  // 4. attn_out -> bf16
  u16* aoc = (u16*)scr;                           // 32MB
  bgemm(stream, mkseg(bf2, outw, 512, 512, 512), Z, Z,
        out_b, nullptr, nullptr, nullptr, nullptr, nullptr, aoc, nullptr,
        Mtok, 512, 512, 0, 0, 0, 0, 1.f, 0, 1);

  // 5. x1 = LN(h + attn_out) -> hi (in place) + lo (lob; vT consumed)
  ln1_k<<<Mtok, 256, 0, stream>>>(bf1, aoc, ln1_g, ln1_b, bf1, lob);

  // 6+7. FFN
  u16* mid = (u16*)scr;                           // 64MB
  bgemm(stream, mkseg(bf1, fw1b, 512, 512, 512), Z, Z,
        fb1, nullptr, nullptr, nullptr, nullptr, nullptr, mid, nullptr,
        Mtok, 1024, 1024, 0, 0, 0, 0, 1.f, F_RELU, 1);
  bgemm(stream, mkseg(mid, fw2b, 1024, 1024, 1024), Z, Z,
        fb2, bf1, lob, nullptr, nullptr, nullptr, bf1, lob,
        Mtok, 512, 512, 0, 0, 0, 0, 1.f, F_RESID2, 1);

  // 8. row norms
  rownorm_k<<<Mtok, 256, 0, stream>>>(bf1, lob, invn);

  // 9-12. graph: x1T once, then 2 chunks x 16 batches; sim bf16 in-place adj
  u16* simadj = (u16*)scr;                        // 32MB (16 x 1024x1024 u16)
  u16* x1T    = (u16*)(scr + 33554432);           // 32MB (all 32 batches)
  transp_k<<<dim3(16, 8, 32), 256, 0, stream>>>(bf1, x1T, 512, 1024,
                                                524288, 524288);
  for (int g = 0; g < 2; ++g) {
    long row0 = (long)g * 16384;
    // sim = (hi.hi^T) * invn_i * invn_j  -> bf16
    bgemm(stream,
          mkseg(bf1 + row0 * 512, bf1 + row0 * 512, 512, 512, 512, 524288, 524288),
          Z, Z, nullptr, nullptr, nullptr, invn + row0, invn + row0,
          nullptr, simadj, nullptr,
          1024, 1024, 1024, 1048576, 0, 0, 1024, 1.f, F_SIMSC, 16);
    topk_k<<<16384, 256, 0, stream>>>(simadj, idx4 + row0 * 4);
    adjbf_k<<<16384, 256, 0, stream>>>(simadj, idx4 + row0 * 4, invcnt + row0);
    // nsum = (adj @ x1) * invcnt
    bgemm(stream, mkseg(simadj, x1T + row0 * 512, 1024, 1024, 1024,
                        1048576, 524288), Z, Z,
          nullptr, nullptr, nullptr, invcnt + row0, nullptr, nullptr,
          bf2 + row0 * 512, nullptr,
          1024, 512, 512, 524288, 0, 0, 1024, 1.f, F_ROWSC, 16);
  }

  // 13/14. gcout = x1_hi @ gcW1^T + nsum @ gcW2^T + gc_b  (2-seg) -> bf16
  u16* gch = (u16*)scr;                           // 32MB
  bgemm(stream, mkseg(bf1, gcwb, 512, 512, 1024),
        mkseg(bf2, gcwb + 512, 512, 512, 1024), Z,
        gc_b, nullptr, nullptr, nullptr, nullptr, nullptr, gch, nullptr,
        Mtok, 512, 512, 0, 0, 0, 0, 1.f, 0, 1);

  // 15. x2 = LN(x1 + gcout) -> bf16 (over bf2; nsum consumed)
  ln2_k<<<Mtok, 256, 0, stream>>>(bf1, lob, gch, ln2_g, ln2_b, bf2);

  // 16+17. pool + decoder
  poolbf_k<<<128, 256, 0, stream>>>(bf2, pooledb);
  bgemm(stream, mkseg(pooledb, decw, 512, 512, 512), Z, Z,
        dec_b, nullptr, nullptr, nullptr, nullptr, out, nullptr, nullptr,
        128, 512, 512, 0, 0, 0, 0, 1.f, 0, 1, 32);
}